// Round 2
// baseline (300.334 us; speedup 1.0000x reference)
//
#include <hip/hip_runtime.h>
#include <math.h>

// MambaBlock, fp32 in/out, bf16 MFMA compute.
// uv = x @ Wi^T + bi ; u,v = split(uv) ; y = silu(dwconv3(v)+bc)*u ; out = y @ Wo^T + bo
// B=4, L=4096, D=1024 -> M = 16384 rows; GEMM1 N=2048, GEMM2 N=1024, K=1024.
//
// ws layout (bf16 shorts):
//   uv  [16384][2048]  at 0        (64 MiB)
//   xb  [16384][1024]  at 32M sh   (32 MiB)  -- reused as yb after GEMM1
//   Wib [2048][1024]                (4 MiB)
//   Wob [1024][1024]                (2 MiB)
// total 102 MiB.

typedef __attribute__((ext_vector_type(8))) short short8;
typedef __attribute__((ext_vector_type(4))) float floatx4;

__device__ __forceinline__ float b2f(short s) {
    unsigned int u = ((unsigned int)(unsigned short)s) << 16;
    float f;
    __builtin_memcpy(&f, &u, 4);
    return f;
}

__device__ __forceinline__ short f2b(float f) {
    unsigned int u;
    __builtin_memcpy(&u, &f, 4);
    u += 0x7fffu + ((u >> 16) & 1u);   // round-to-nearest-even
    return (short)(u >> 16);
}

// async 16B/lane global->LDS; LDS dest = wave-uniform base + lane*16B.
__device__ __forceinline__ void gl_lds16(const short* g, short* l) {
    __builtin_amdgcn_global_load_lds(
        (const __attribute__((address_space(1))) unsigned int*)g,
        (__attribute__((address_space(3))) unsigned int*)l,
        16, 0, 0);
}

// fp32 -> bf16 conversion, 8 elems/thread. n8 = n/8 (exact for all our sizes).
__global__ __launch_bounds__(256) void cvt_f32_bf16(
    const float* __restrict__ in, short* __restrict__ out, int n8)
{
    int i = blockIdx.x * 256 + threadIdx.x;
    if (i >= n8) return;
    float4 a = ((const float4*)in)[2 * i];
    float4 b = ((const float4*)in)[2 * i + 1];
    short8 o;
    o[0] = f2b(a.x); o[1] = f2b(a.y); o[2] = f2b(a.z); o[3] = f2b(a.w);
    o[4] = f2b(b.x); o[5] = f2b(b.y); o[6] = f2b(b.z); o[7] = f2b(b.w);
    ((short8*)out)[i] = o;
}

// C[m][n] = sum_k A[m][k]*B[n][k] + bias[n].  A,B bf16 (B row-major [N][K]).
// OUTF32: C fp32, else C bf16. 128x128 tile, BK=32, 4 waves of 4x4 16x16x32 MFMA.
template <bool OUTF32>
__global__ __launch_bounds__(256, 2) void gemm_bt(
    const short* __restrict__ A, const short* __restrict__ B,
    const float* __restrict__ bias, void* __restrict__ Cv,
    int lda, int ldb, int ldc)
{
    constexpr int K = 1024;
    __shared__ __attribute__((aligned(16))) short As[128 * 32];
    __shared__ __attribute__((aligned(16))) short Bs[128 * 32];

    const int tid  = threadIdx.x;
    const int wave = tid >> 6;
    const int lane = tid & 63;
    const int mBase = blockIdx.x * 128;
    const int nBase = blockIdx.y * 128;

    floatx4 acc[4][4];
#pragma unroll
    for (int i = 0; i < 4; i++)
#pragma unroll
        for (int j = 0; j < 4; j++) acc[i][j] = {0.f, 0.f, 0.f, 0.f};

    // staging: wave w covers tile rows [32w, 32w+32): two 16-row async loads each
    // for A and B. lane -> row 32w + (lane>>2), col (lane&3)*8 elems; HW scatters
    // lane i to ldsbase + 16B*i which equals row-major [row][col] exactly.
    const int sRow = wave * 32 + (lane >> 2);
    const int sCol = (lane & 3) * 8;
    const short* gA = A + (size_t)(mBase + sRow) * lda + sCol;
    const short* gB = B + (size_t)(nBase + sRow) * ldb + sCol;
    short* lA = &As[(wave * 32) * 32];
    short* lB = &Bs[(wave * 32) * 32];

    const int mq = (wave & 1) * 64;
    const int nq = (wave >> 1) * 64;
    const int fRow = lane & 15;          // m (or n) within a 16-tile
    const int fK   = (lane >> 4) * 8;    // k start within 32

    for (int k0 = 0; k0 < K; k0 += 32) {
        __syncthreads();                       // previous tile fully consumed
        gl_lds16(gA + k0,            lA);
        gl_lds16(gA + 16 * lda + k0, lA + 16 * 32);
        gl_lds16(gB + k0,            lB);
        gl_lds16(gB + 16 * ldb + k0, lB + 16 * 32);
        __syncthreads();                       // compiler drains vmcnt(0) here

        short8 a[4], b[4];
#pragma unroll
        for (int mi = 0; mi < 4; mi++)
            a[mi] = *(const short8*)&As[(mq + mi * 16 + fRow) * 32 + fK];
#pragma unroll
        for (int ni = 0; ni < 4; ni++)
            b[ni] = *(const short8*)&Bs[(nq + ni * 16 + fRow) * 32 + fK];
#pragma unroll
        for (int mi = 0; mi < 4; mi++)
#pragma unroll
            for (int ni = 0; ni < 4; ni++)
                acc[mi][ni] = __builtin_amdgcn_mfma_f32_16x16x32_bf16(
                    a[mi], b[ni], acc[mi][ni], 0, 0, 0);
    }

    // C/D layout: col = lane&15, row = (lane>>4)*4 + reg   [m89/m91-verified]
    const int colq = lane & 15;
    const int rowq = (lane >> 4) * 4;
#pragma unroll
    for (int ni = 0; ni < 4; ni++) {
        const int col = nBase + nq + ni * 16 + colq;
        const float bv = bias[col];
#pragma unroll
        for (int mi = 0; mi < 4; mi++) {
            const int row = mBase + mq + mi * 16 + rowq;
#pragma unroll
            for (int r = 0; r < 4; r++) {
                float v = acc[mi][ni][r] + bv;
                if (OUTF32)
                    ((float*)Cv)[(size_t)(row + r) * ldc + col] = v;
                else
                    ((short*)Cv)[(size_t)(row + r) * ldc + col] = f2b(v);
            }
        }
    }
}

// y[m][d] = silu( v[m-1]*w0 + v[m]*w1 + v[m+1]*w2 + bc ) * u[m][d]
// uv bf16 [16384][2048] (u cols 0..1023, v cols 1024..2047); Wc/bc fp32;
// y written bf16 to yb [16384][1024]. 8 channels per thread.
__global__ __launch_bounds__(256) void conv_gate(
    const short* __restrict__ uv, const float* __restrict__ Wc,
    const float* __restrict__ bc, short* __restrict__ yb)
{
    const int idx = blockIdx.x * 256 + threadIdx.x;
    const int d8 = idx & 127;
    const int m  = idx >> 7;
    const int l  = m & 4095;             // L = 4096, zero-pad at batch edges
    const int d  = d8 * 8;

    // Wc[d..d+7][0][0..2]: 24 contiguous floats, 16B-aligned (96B * d8)
    float w[24];
#pragma unroll
    for (int q = 0; q < 6; q++)
        *(float4*)&w[q * 4] = ((const float4*)(Wc + d * 3))[q];
    float bcv[8];
    *(float4*)&bcv[0] = ((const float4*)(bc + d))[0];
    *(float4*)&bcv[4] = ((const float4*)(bc + d))[1];

    const size_t rowu = (size_t)m * 2048 + d;
    const size_t rowv = rowu + 1024;

    const short8 z = {0, 0, 0, 0, 0, 0, 0, 0};
    const short8 us = *(const short8*)(uv + rowu);
    const short8 vc = *(const short8*)(uv + rowv);
    const short8 vm = (l > 0)    ? *(const short8*)(uv + rowv - 2048) : z;
    const short8 vp = (l < 4095) ? *(const short8*)(uv + rowv + 2048) : z;

    short8 outv;
#pragma unroll
    for (int j = 0; j < 8; j++) {
        float y = b2f(vm[j]) * w[j * 3 + 0]
                + b2f(vc[j]) * w[j * 3 + 1]
                + b2f(vp[j]) * w[j * 3 + 2]
                + bcv[j];
        float sil = y / (1.0f + expf(-y));
        outv[j] = f2b(sil * b2f(us[j]));
    }
    *(short8*)(yb + (size_t)m * 1024 + d) = outv;
}

extern "C" void kernel_launch(void* const* d_in, const int* in_sizes, int n_in,
                              void* d_out, int out_size, void* d_ws, size_t ws_size,
                              hipStream_t stream)
{
    const float* x  = (const float*)d_in[0];   // [4,4096,1024]
    const float* Wi = (const float*)d_in[1];   // [2048,1024]
    const float* bi = (const float*)d_in[2];   // [2048]
    const float* Wc = (const float*)d_in[3];   // [1024,1,3]
    const float* bc = (const float*)d_in[4];   // [1024]
    const float* Wo = (const float*)d_in[5];   // [1024,1024]
    const float* bo = (const float*)d_in[6];   // [1024]
    float* out = (float*)d_out;                // [4,4096,1024] fp32

    short* wsS = (short*)d_ws;
    short* uv  = wsS;                          // 16384*2048
    short* xb  = uv + (size_t)16384 * 2048;    // 16384*1024 (later: yb)
    short* Wib = xb + (size_t)16384 * 1024;    // 2048*1024
    short* Wob = Wib + (size_t)2048 * 1024;    // 1024*1024

    dim3 blk(256);

    // bf16 conversions
    cvt_f32_bf16<<<(16384 * 1024 / 8 + 255) / 256, blk, 0, stream>>>(x,  xb,  16384 * 1024 / 8);
    cvt_f32_bf16<<<(2048 * 1024 / 8 + 255) / 256,  blk, 0, stream>>>(Wi, Wib, 2048 * 1024 / 8);
    cvt_f32_bf16<<<(1024 * 1024 / 8 + 255) / 256,  blk, 0, stream>>>(Wo, Wob, 1024 * 1024 / 8);

    // GEMM1: uv = xb @ Wib^T + bi   (M=16384, N=2048, K=1024), bf16 out
    dim3 g1(16384 / 128, 2048 / 128);
    gemm_bt<false><<<g1, blk, 0, stream>>>(xb, Wib, bi, uv, 1024, 1024, 2048);

    // conv + silu gate -> yb (reuses xb region; xb dead after GEMM1)
    conv_gate<<<(16384 * 128) / 256, blk, 0, stream>>>(uv, Wc, bc, xb);

    // GEMM2: out = yb @ Wob^T + bo  (M=16384, N=1024, K=1024), fp32 out
    dim3 g2(16384 / 128, 1024 / 128);
    gemm_bt<true><<<g2, blk, 0, stream>>>(xb, Wob, bo, out, 1024, 1024, 1024);
}

// Round 3
// 297.601 us; speedup vs baseline: 1.0092x; 1.0092x over previous
//
#include <hip/hip_runtime.h>
#include <math.h>

// MambaBlock, fp32 in/out, bf16 MFMA compute.
// uv = x @ Wi^T + bi ; u,v = split(uv) ; y = silu(dwconv3(v)+bc)*u ; out = y @ Wo^T + bo
// B=4, L=4096, D=1024 -> M = 16384 rows; GEMM1 N=2048, GEMM2 N=1024, K=1024.
//
// ws layout (bf16 shorts): uv[16384][2048] | xb[16384][1024] (reused as yb) |
// Wib[2048][1024] | Wob[1024][1024]  = 102 MiB total.
//
// LDS tiles use a XOR-swizzle on 16B column groups: physical group pg of row r
// holds logical group pg ^ ((r>>1)&3). Staging permutes per-lane SOURCE addrs
// (HW lane->LDS dest mapping untouched); reads apply the same XOR. This spreads
// each 8-lane ds_read_b128 service group across all 8 bank-slots (was 4-way).

typedef __attribute__((ext_vector_type(8))) short short8;
typedef __attribute__((ext_vector_type(4))) float floatx4;

__device__ __forceinline__ float b2f(short s) {
    unsigned int u = ((unsigned int)(unsigned short)s) << 16;
    float f;
    __builtin_memcpy(&f, &u, 4);
    return f;
}

__device__ __forceinline__ short f2b(float f) {
    unsigned int u;
    __builtin_memcpy(&u, &f, 4);
    u += 0x7fffu + ((u >> 16) & 1u);   // round-to-nearest-even
    return (short)(u >> 16);
}

// async 16B/lane global->LDS; LDS dest = wave-uniform base + lane*16B.
__device__ __forceinline__ void gl_lds16(const short* g, short* l) {
    __builtin_amdgcn_global_load_lds(
        (const __attribute__((address_space(1))) unsigned int*)g,
        (__attribute__((address_space(3))) unsigned int*)l,
        16, 0, 0);
}

// single fp32->bf16 conversion pass over x, Wi, Wo (8 elems/thread)
__global__ __launch_bounds__(256) void cvt_all(
    const float* __restrict__ x, const float* __restrict__ Wi,
    const float* __restrict__ Wo, short* __restrict__ xb,
    short* __restrict__ Wib, short* __restrict__ Wob)
{
    constexpr int n1 = 16384 * 1024 / 8;
    constexpr int n2 = 2048 * 1024 / 8;
    constexpr int n3 = 1024 * 1024 / 8;
    int i = blockIdx.x * 256 + threadIdx.x;
    const float* src;
    short* dst;
    int j;
    if (i < n1)           { src = x;  dst = xb;  j = i; }
    else if (i < n1 + n2) { src = Wi; dst = Wib; j = i - n1; }
    else if (i < n1 + n2 + n3) { src = Wo; dst = Wob; j = i - n1 - n2; }
    else return;
    float4 a = ((const float4*)src)[2 * j];
    float4 b = ((const float4*)src)[2 * j + 1];
    short8 o;
    o[0] = f2b(a.x); o[1] = f2b(a.y); o[2] = f2b(a.z); o[3] = f2b(a.w);
    o[4] = f2b(b.x); o[5] = f2b(b.y); o[6] = f2b(b.z); o[7] = f2b(b.w);
    ((short8*)dst)[j] = o;
}

// C[m][n] = sum_k A[m][k]*B[n][k] + bias[n].  A,B bf16 (B row-major [N][K]).
// OUTF32: C fp32, else C bf16. 128x128 tile, BK=32, 4 waves of 4x4 16x16x32 MFMA.
template <bool OUTF32>
__global__ __launch_bounds__(256, 2) void gemm_bt(
    const short* __restrict__ A, const short* __restrict__ B,
    const float* __restrict__ bias, void* __restrict__ Cv,
    int lda, int ldb, int ldc)
{
    constexpr int K = 1024;
    __shared__ __attribute__((aligned(16))) short As[128 * 32];
    __shared__ __attribute__((aligned(16))) short Bs[128 * 32];

    const int tid  = threadIdx.x;
    const int wave = tid >> 6;
    const int lane = tid & 63;
    const int mBase = blockIdx.x * 128;
    const int nBase = blockIdx.y * 128;

    floatx4 acc[4][4];
#pragma unroll
    for (int i = 0; i < 4; i++)
#pragma unroll
        for (int j = 0; j < 4; j++) acc[i][j] = {0.f, 0.f, 0.f, 0.f};

    // staging: wave w covers tile rows [32w, 32w+32), two 16-row async loads
    // each for A and B. Physical LDS slot for lane = contiguous 16B; the SOURCE
    // column group is XOR-swizzled: lg = (lane&3) ^ ((sRow>>1)&3).
    // sRow = wave*32 + (lane>>2)  ->  (sRow>>1)&3 == (lane>>3)&3.
    const int sRow = wave * 32 + (lane >> 2);
    const int sCol = (((lane & 3) ^ ((lane >> 3) & 3))) * 8;
    const short* gA = A + (size_t)(mBase + sRow) * lda + sCol;
    const short* gB = B + (size_t)(nBase + sRow) * ldb + sCol;
    short* lA = &As[(wave * 32) * 32];
    short* lB = &Bs[(wave * 32) * 32];
    // note: rows +16 have the same swizzle ((r+16)>>1)&3 == (r>>1)&3.

    const int mq = (wave & 1) * 64;
    const int nq = (wave >> 1) * 64;
    const int fRow = lane & 15;          // m (or n) within a 16-tile
    const int lg   = lane >> 4;          // logical 8-elem k-group within BK=32
    const int swz  = (fRow >> 1) & 3;    // row-dependent group swizzle
    const int fOff = (lg ^ swz) * 8;     // physical k-offset in LDS row

    for (int k0 = 0; k0 < K; k0 += 32) {
        __syncthreads();                       // previous tile fully consumed
        gl_lds16(gA + k0,            lA);
        gl_lds16(gA + 16 * lda + k0, lA + 16 * 32);
        gl_lds16(gB + k0,            lB);
        gl_lds16(gB + 16 * ldb + k0, lB + 16 * 32);
        __syncthreads();                       // drains vmcnt(0) before barrier

        short8 a[4], b[4];
#pragma unroll
        for (int mi = 0; mi < 4; mi++)
            a[mi] = *(const short8*)&As[(mq + mi * 16 + fRow) * 32 + fOff];
#pragma unroll
        for (int ni = 0; ni < 4; ni++)
            b[ni] = *(const short8*)&Bs[(nq + ni * 16 + fRow) * 32 + fOff];
#pragma unroll
        for (int mi = 0; mi < 4; mi++)
#pragma unroll
            for (int ni = 0; ni < 4; ni++)
                acc[mi][ni] = __builtin_amdgcn_mfma_f32_16x16x32_bf16(
                    a[mi], b[ni], acc[mi][ni], 0, 0, 0);
    }

    // C/D layout: col = lane&15, row = (lane>>4)*4 + reg   [m89/m91-verified]
    const int colq = lane & 15;
    const int rowq = (lane >> 4) * 4;
#pragma unroll
    for (int ni = 0; ni < 4; ni++) {
        const int col = nBase + nq + ni * 16 + colq;
        const float bv = bias[col];
#pragma unroll
        for (int mi = 0; mi < 4; mi++) {
            const int row = mBase + mq + mi * 16 + rowq;
#pragma unroll
            for (int r = 0; r < 4; r++) {
                float v = acc[mi][ni][r] + bv;
                if (OUTF32)
                    ((float*)Cv)[(size_t)(row + r) * ldc + col] = v;
                else
                    ((short*)Cv)[(size_t)(row + r) * ldc + col] = f2b(v);
            }
        }
    }
}

// y[m][d] = silu( v[m-1]*w0 + v[m]*w1 + v[m+1]*w2 + bc ) * u[m][d]
// uv bf16 [16384][2048] (u cols 0..1023, v cols 1024..2047); Wc/bc fp32;
// y written bf16 to yb [16384][1024]. 8 channels per thread.
__global__ __launch_bounds__(256) void conv_gate(
    const short* __restrict__ uv, const float* __restrict__ Wc,
    const float* __restrict__ bc, short* __restrict__ yb)
{
    const int idx = blockIdx.x * 256 + threadIdx.x;
    const int d8 = idx & 127;
    const int m  = idx >> 7;
    const int l  = m & 4095;             // L = 4096, zero-pad at batch edges
    const int d  = d8 * 8;

    float w[24];
#pragma unroll
    for (int q = 0; q < 6; q++)
        *(float4*)&w[q * 4] = ((const float4*)(Wc + d * 3))[q];
    float bcv[8];
    *(float4*)&bcv[0] = ((const float4*)(bc + d))[0];
    *(float4*)&bcv[4] = ((const float4*)(bc + d))[1];

    const size_t rowu = (size_t)m * 2048 + d;
    const size_t rowv = rowu + 1024;

    const short8 z = {0, 0, 0, 0, 0, 0, 0, 0};
    const short8 us = *(const short8*)(uv + rowu);
    const short8 vc = *(const short8*)(uv + rowv);
    const short8 vm = (l > 0)    ? *(const short8*)(uv + rowv - 2048) : z;
    const short8 vp = (l < 4095) ? *(const short8*)(uv + rowv + 2048) : z;

    short8 outv;
#pragma unroll
    for (int j = 0; j < 8; j++) {
        float y = b2f(vm[j]) * w[j * 3 + 0]
                + b2f(vc[j]) * w[j * 3 + 1]
                + b2f(vp[j]) * w[j * 3 + 2]
                + bcv[j];
        float sil = y / (1.0f + expf(-y));
        outv[j] = f2b(sil * b2f(us[j]));
    }
    *(short8*)(yb + (size_t)m * 1024 + d) = outv;
}

extern "C" void kernel_launch(void* const* d_in, const int* in_sizes, int n_in,
                              void* d_out, int out_size, void* d_ws, size_t ws_size,
                              hipStream_t stream)
{
    const float* x  = (const float*)d_in[0];   // [4,4096,1024]
    const float* Wi = (const float*)d_in[1];   // [2048,1024]
    const float* bi = (const float*)d_in[2];   // [2048]
    const float* Wc = (const float*)d_in[3];   // [1024,1,3]
    const float* bc = (const float*)d_in[4];   // [1024]
    const float* Wo = (const float*)d_in[5];   // [1024,1024]
    const float* bo = (const float*)d_in[6];   // [1024]
    float* out = (float*)d_out;                // [4,4096,1024] fp32

    short* wsS = (short*)d_ws;
    short* uv  = wsS;                          // 16384*2048
    short* xb  = uv + (size_t)16384 * 2048;    // 16384*1024 (later: yb)
    short* Wib = xb + (size_t)16384 * 1024;    // 2048*1024
    short* Wob = Wib + (size_t)2048 * 1024;    // 1024*1024

    dim3 blk(256);

    // one fused bf16 conversion pass (x, Wi, Wo)
    constexpr int nCvt = (16384 * 1024 + 2048 * 1024 + 1024 * 1024) / 8;
    cvt_all<<<(nCvt + 255) / 256, blk, 0, stream>>>(x, Wi, Wo, xb, Wib, Wob);

    // GEMM1: uv = xb @ Wib^T + bi   (M=16384, N=2048, K=1024), bf16 out
    dim3 g1(16384 / 128, 2048 / 128);
    gemm_bt<false><<<g1, blk, 0, stream>>>(xb, Wib, bi, uv, 1024, 1024, 2048);

    // conv + silu gate -> yb (reuses xb region; xb dead after GEMM1)
    conv_gate<<<(16384 * 128) / 256, blk, 0, stream>>>(uv, Wc, bc, xb);

    // GEMM2: out = yb @ Wob^T + bo  (M=16384, N=1024, K=1024), fp32 out
    dim3 g2(16384 / 128, 1024 / 128);
    gemm_bt<true><<<g2, blk, 0, stream>>>(xb, Wob, bo, out, 1024, 1024, 1024);
}

// Round 4
// 281.900 us; speedup vs baseline: 1.0654x; 1.0557x over previous
//
#include <hip/hip_runtime.h>
#include <math.h>

// MambaBlock, fp32 in/out, bf16 MFMA compute.
// uv = x @ Wi^T + bi ; u,v = split(uv) ; y = silu(dwconv3(v)+bc)*u ; out = y @ Wo^T + bo
// B=4, L=4096, D=1024 -> M = 16384 rows; GEMM1 N=2048, GEMM2 N=1024, K=1024.
//
// ws layout (bf16 shorts): uv[16384][2048] | xb[16384][1024] (reused as yb) |
// Wib[2048][1024] | Wob[1024][1024]  = 102 MiB total.
//
// GEMM: 128x128 tile, BK=64, 16 k-iters (halved barrier-drain count vs BK=32).
// LDS XOR swizzle for 128B rows: logical 16B group g of row r at physical
// g ^ (r&7) -> ds_read_b128 8-lane service groups hit all 8 bank-slots.
// Grid axes: x = N-blocks, y = M-blocks => XCD = x%8 keeps each B-panel column
// permanently resident in one XCD's L2; A-panel shared by concurrent same-y run.

typedef __attribute__((ext_vector_type(8))) short short8;
typedef __attribute__((ext_vector_type(4))) float floatx4;

__device__ __forceinline__ float b2f(short s) {
    unsigned int u = ((unsigned int)(unsigned short)s) << 16;
    float f;
    __builtin_memcpy(&f, &u, 4);
    return f;
}

__device__ __forceinline__ short f2b(float f) {
    unsigned int u;
    __builtin_memcpy(&u, &f, 4);
    u += 0x7fffu + ((u >> 16) & 1u);   // round-to-nearest-even
    return (short)(u >> 16);
}

// async 16B/lane global->LDS; LDS dest = wave-uniform base + lane*16B.
__device__ __forceinline__ void gl_lds16(const short* g, short* l) {
    __builtin_amdgcn_global_load_lds(
        (const __attribute__((address_space(1))) unsigned int*)g,
        (__attribute__((address_space(3))) unsigned int*)l,
        16, 0, 0);
}

// single fp32->bf16 conversion pass over x, Wi, Wo (8 elems/thread)
__global__ __launch_bounds__(256) void cvt_all(
    const float* __restrict__ x, const float* __restrict__ Wi,
    const float* __restrict__ Wo, short* __restrict__ xb,
    short* __restrict__ Wib, short* __restrict__ Wob)
{
    constexpr int n1 = 16384 * 1024 / 8;
    constexpr int n2 = 2048 * 1024 / 8;
    constexpr int n3 = 1024 * 1024 / 8;
    int i = blockIdx.x * 256 + threadIdx.x;
    const float* src;
    short* dst;
    int j;
    if (i < n1)           { src = x;  dst = xb;  j = i; }
    else if (i < n1 + n2) { src = Wi; dst = Wib; j = i - n1; }
    else if (i < n1 + n2 + n3) { src = Wo; dst = Wob; j = i - n1 - n2; }
    else return;
    float4 a = ((const float4*)src)[2 * j];
    float4 b = ((const float4*)src)[2 * j + 1];
    short8 o;
    o[0] = f2b(a.x); o[1] = f2b(a.y); o[2] = f2b(a.z); o[3] = f2b(a.w);
    o[4] = f2b(b.x); o[5] = f2b(b.y); o[6] = f2b(b.z); o[7] = f2b(b.w);
    ((short8*)dst)[j] = o;
}

// C[m][n] = sum_k A[m][k]*B[n][k] + bias[n].  A,B bf16 (B row-major [N][K]).
// OUTF32: C fp32, else C bf16. 128x128 tile, BK=64, 4 waves of 4x4 16x16x32 MFMA
// (two k-halves per iter). blockIdx.x -> N, blockIdx.y -> M.
template <bool OUTF32>
__global__ __launch_bounds__(256, 3) void gemm_bt(
    const short* __restrict__ A, const short* __restrict__ B,
    const float* __restrict__ bias, void* __restrict__ Cv,
    int lda, int ldb, int ldc)
{
    constexpr int K = 1024;
    __shared__ __attribute__((aligned(16))) short As[128 * 64];
    __shared__ __attribute__((aligned(16))) short Bs[128 * 64];

    const int tid  = threadIdx.x;
    const int wave = tid >> 6;
    const int lane = tid & 63;
    const int mBase = blockIdx.y * 128;
    const int nBase = blockIdx.x * 128;

    floatx4 acc[4][4];
#pragma unroll
    for (int i = 0; i < 4; i++)
#pragma unroll
        for (int j = 0; j < 4; j++) acc[i][j] = {0.f, 0.f, 0.f, 0.f};

    // staging (BK=64): wave w stages rows [32w,32w+32) of A and B as 4 async
    // instrs each (1KB = 8 rows x 128B per instr). lane -> row +(lane>>3),
    // source 16B group (lane&7) ^ ((lane>>3)&7)  [dest group lane&7 => the
    // XOR-swizzle: logical g at physical g ^ (row&7); base rows are 8-aligned].
    const int sRow = wave * 32 + (lane >> 3);
    const int sg   = (((lane & 7) ^ ((lane >> 3) & 7))) * 8;
    const short* gA = A + (size_t)(mBase + sRow) * lda + sg;
    const short* gB = B + (size_t)(nBase + sRow) * ldb + sg;
    short* lA = &As[(wave * 32) * 64];
    short* lB = &Bs[(wave * 32) * 64];

    const int mq = (wave & 1) * 64;
    const int nq = (wave >> 1) * 64;
    const int fRow = lane & 15;          // m (or n) within a 16-tile
    const int lg   = lane >> 4;          // logical 8-elem k-group (0..3) in a half
    // physical group offset for k-half 0; half 1 is p0 ^ 32 (shorts)
    const int p0   = ((lg ^ (fRow & 7))) * 8;

    for (int k0 = 0; k0 < K; k0 += 64) {
        __syncthreads();                       // previous tile fully consumed
#pragma unroll
        for (int j = 0; j < 4; j++) {
            gl_lds16(gA + (size_t)(8 * j) * lda + k0, lA + 8 * j * 64);
            gl_lds16(gB + (size_t)(8 * j) * ldb + k0, lB + 8 * j * 64);
        }
        __syncthreads();                       // drains vmcnt(0) before barrier

#pragma unroll
        for (int h = 0; h < 2; h++) {
            const int po = p0 ^ (h * 32);
            short8 a[4], b[4];
#pragma unroll
            for (int mi = 0; mi < 4; mi++)
                a[mi] = *(const short8*)&As[(mq + mi * 16 + fRow) * 64 + po];
#pragma unroll
            for (int ni = 0; ni < 4; ni++)
                b[ni] = *(const short8*)&Bs[(nq + ni * 16 + fRow) * 64 + po];
#pragma unroll
            for (int mi = 0; mi < 4; mi++)
#pragma unroll
                for (int ni = 0; ni < 4; ni++)
                    acc[mi][ni] = __builtin_amdgcn_mfma_f32_16x16x32_bf16(
                        a[mi], b[ni], acc[mi][ni], 0, 0, 0);
        }
    }

    // C/D layout: col = lane&15, row = (lane>>4)*4 + reg   [m89/m91-verified]
    const int colq = lane & 15;
    const int rowq = (lane >> 4) * 4;
#pragma unroll
    for (int ni = 0; ni < 4; ni++) {
        const int col = nBase + nq + ni * 16 + colq;
        const float bv = bias[col];
#pragma unroll
        for (int mi = 0; mi < 4; mi++) {
            const int row = mBase + mq + mi * 16 + rowq;
#pragma unroll
            for (int r = 0; r < 4; r++) {
                float v = acc[mi][ni][r] + bv;
                if (OUTF32)
                    ((float*)Cv)[(size_t)(row + r) * ldc + col] = v;
                else
                    ((short*)Cv)[(size_t)(row + r) * ldc + col] = f2b(v);
            }
        }
    }
}

// y[m][d] = silu( v[m-1]*w0 + v[m]*w1 + v[m+1]*w2 + bc ) * u[m][d]
// uv bf16 [16384][2048] (u cols 0..1023, v cols 1024..2047); Wc/bc fp32;
// y written bf16 to yb [16384][1024]. 8 channels per thread.
__global__ __launch_bounds__(256) void conv_gate(
    const short* __restrict__ uv, const float* __restrict__ Wc,
    const float* __restrict__ bc, short* __restrict__ yb)
{
    const int idx = blockIdx.x * 256 + threadIdx.x;
    const int d8 = idx & 127;
    const int m  = idx >> 7;
    const int l  = m & 4095;             // L = 4096, zero-pad at batch edges
    const int d  = d8 * 8;

    float w[24];
#pragma unroll
    for (int q = 0; q < 6; q++)
        *(float4*)&w[q * 4] = ((const float4*)(Wc + d * 3))[q];
    float bcv[8];
    *(float4*)&bcv[0] = ((const float4*)(bc + d))[0];
    *(float4*)&bcv[4] = ((const float4*)(bc + d))[1];

    const size_t rowu = (size_t)m * 2048 + d;
    const size_t rowv = rowu + 1024;

    const short8 z = {0, 0, 0, 0, 0, 0, 0, 0};
    const short8 us = *(const short8*)(uv + rowu);
    const short8 vc = *(const short8*)(uv + rowv);
    const short8 vm = (l > 0)    ? *(const short8*)(uv + rowv - 2048) : z;
    const short8 vp = (l < 4095) ? *(const short8*)(uv + rowv + 2048) : z;

    short8 outv;
#pragma unroll
    for (int j = 0; j < 8; j++) {
        float y = b2f(vm[j]) * w[j * 3 + 0]
                + b2f(vc[j]) * w[j * 3 + 1]
                + b2f(vp[j]) * w[j * 3 + 2]
                + bcv[j];
        float sil = y / (1.0f + expf(-y));
        outv[j] = f2b(sil * b2f(us[j]));
    }
    *(short8*)(yb + (size_t)m * 1024 + d) = outv;
}

extern "C" void kernel_launch(void* const* d_in, const int* in_sizes, int n_in,
                              void* d_out, int out_size, void* d_ws, size_t ws_size,
                              hipStream_t stream)
{
    const float* x  = (const float*)d_in[0];   // [4,4096,1024]
    const float* Wi = (const float*)d_in[1];   // [2048,1024]
    const float* bi = (const float*)d_in[2];   // [2048]
    const float* Wc = (const float*)d_in[3];   // [1024,1,3]
    const float* bc = (const float*)d_in[4];   // [1024]
    const float* Wo = (const float*)d_in[5];   // [1024,1024]
    const float* bo = (const float*)d_in[6];   // [1024]
    float* out = (float*)d_out;                // [4,4096,1024] fp32

    short* wsS = (short*)d_ws;
    short* uv  = wsS;                          // 16384*2048
    short* xb  = uv + (size_t)16384 * 2048;    // 16384*1024 (later: yb)
    short* Wib = xb + (size_t)16384 * 1024;    // 2048*1024
    short* Wob = Wib + (size_t)2048 * 1024;    // 1024*1024

    dim3 blk(256);

    // one fused bf16 conversion pass (x, Wi, Wo)
    constexpr int nCvt = (16384 * 1024 + 2048 * 1024 + 1024 * 1024) / 8;
    cvt_all<<<(nCvt + 255) / 256, blk, 0, stream>>>(x, Wi, Wo, xb, Wib, Wob);

    // GEMM1: uv = xb @ Wib^T + bi   (M=16384, N=2048, K=1024), bf16 out
    dim3 g1(2048 / 128, 16384 / 128);          // x = N-blocks, y = M-blocks
    gemm_bt<false><<<g1, blk, 0, stream>>>(xb, Wib, bi, uv, 1024, 1024, 2048);

    // conv + silu gate -> yb (reuses xb region; xb dead after GEMM1)
    conv_gate<<<(16384 * 128) / 256, blk, 0, stream>>>(uv, Wc, bc, xb);

    // GEMM2: out = yb @ Wob^T + bo  (M=16384, N=1024, K=1024), fp32 out
    dim3 g2(1024 / 128, 16384 / 128);
    gemm_bt<true><<<g2, blk, 0, stream>>>(xb, Wob, bo, out, 1024, 1024, 1024);
}